// Round 1
// baseline (473.827 us; speedup 1.0000x reference)
//
#include <hip/hip_runtime.h>
#include <stdint.h>

typedef __attribute__((ext_vector_type(8))) short short8;
typedef __attribute__((ext_vector_type(4))) float floatx4;

#define EPS 1e-8f
#define TAU 0.1f

// float -> bf16 bits, round-to-nearest-even
__device__ __forceinline__ unsigned short f2bf(float f) {
  union { float f; unsigned u; } v; v.f = f;
  unsigned u = v.u;
  u += 0x7fffu + ((u >> 16) & 1u);
  return (unsigned short)(u >> 16);
}

// Kernel 1: normalize prototypes (K=64 x D=256) -> bf16 row-major in ws,
// and zero the f64 loss accumulator. 1 block x 256 threads.
__global__ void proto_prep(const float* __restrict__ protos,
                           unsigned short* __restrict__ pbf,
                           double* __restrict__ acc) {
  const int tid = threadIdx.x;
  const int l = tid & 63, w = tid >> 6;
  if (tid == 0) *acc = 0.0;
  for (int j = 0; j < 16; ++j) {
    const int row = j * 4 + w;                       // wave w owns rows {4j+w}
    float4 v = reinterpret_cast<const float4*>(protos)[row * 64 + l];
    float ss = v.x * v.x + v.y * v.y + v.z * v.z + v.w * v.w;
#pragma unroll
    for (int d = 1; d < 64; d <<= 1) ss += __shfl_xor(ss, d, 64);
    const float inv = 1.0f / fmaxf(sqrtf(ss), 1e-12f);
    ushort4 o;
    o.x = f2bf(v.x * inv); o.y = f2bf(v.y * inv);
    o.z = f2bf(v.z * inv); o.w = f2bf(v.w * inv);
    reinterpret_cast<ushort4*>(pbf)[row * 64 + l] = o;
  }
}

// Kernel 2: main. One block = 64 feature rows. 4 waves; wave w owns M-tile
// rows [w*16, w*16+16). sim = (f_bf16 . p_norm_bf16) / (||f|| * tau).
__global__ __launch_bounds__(256, 4)
void protonce_main(const float* __restrict__ feat,
                   const unsigned short* __restrict__ pbf,
                   const int* __restrict__ labels,
                   double* __restrict__ acc_out) {
  constexpr int LDA = 264;                 // bf16 elems; pad 256->264 for banks
  __shared__ unsigned short Asm[64 * LDA]; // 33792 B
  __shared__ float norms[64];
  __shared__ int labs[64];
  __shared__ float red[256];

  const int tid = threadIdx.x;
  const int l = tid & 63;
  const int w = tid >> 6;
  const int m = l & 15;                    // MFMA n/m low index
  const int q = l >> 4;                    // MFMA quad
  const long tileBase = (long)blockIdx.x * 64;
  const float4* fbase = reinterpret_cast<const float4*>(feat + tileBase * 256);

  if (tid < 64) labs[tid] = labels[tileBase + tid];

  // Stage: wave-inst j reads one full 1KB row (fully coalesced), fp32 norm,
  // convert to bf16 into padded LDS tile.
#pragma unroll
  for (int j = 0; j < 16; ++j) {
    const int row = j * 4 + w;
    float4 v = fbase[row * 64 + l];
    float ss = v.x * v.x + v.y * v.y + v.z * v.z + v.w * v.w;
#pragma unroll
    for (int d = 1; d < 64; d <<= 1) ss += __shfl_xor(ss, d, 64);
    if (l == 0) norms[row] = ss;
    ushort4 o;
    o.x = f2bf(v.x); o.y = f2bf(v.y); o.z = f2bf(v.z); o.w = f2bf(v.w);
    *reinterpret_cast<ushort4*>(&Asm[row * LDA + l * 4]) = o;
  }
  __syncthreads();

  // MFMA: (16 x 256) x (256 x 64) per wave. A from LDS, B straight from
  // global (32KB, L1/L2 resident).
  floatx4 acc[4] = {{0.f, 0.f, 0.f, 0.f}, {0.f, 0.f, 0.f, 0.f},
                    {0.f, 0.f, 0.f, 0.f}, {0.f, 0.f, 0.f, 0.f}};
  const unsigned short* arow = &Asm[(w * 16 + m) * LDA + q * 8];
  const unsigned short* brow = pbf + m * 256 + q * 8;

#pragma unroll
  for (int s = 0; s < 8; ++s) {            // K-step: 8 x 32 = 256
    short8 af = *reinterpret_cast<const short8*>(arow + s * 32);
#pragma unroll
    for (int t = 0; t < 4; ++t) {          // N-tiles: 4 x 16 = 64 protos
      short8 bf = *reinterpret_cast<const short8*>(brow + t * 16 * 256 + s * 32);
      acc[t] = __builtin_amdgcn_mfma_f32_16x16x32_bf16(af, bf, acc[t], 0, 0, 0);
    }
  }

  // Epilogue. Lane holds sim[row = w*16 + q*4 + r][k = t*16 + m].
  float lossAcc = 0.f;
#pragma unroll
  for (int r = 0; r < 4; ++r) {
    const int row = w * 16 + q * 4 + r;
    const float sc = 1.0f / (fmaxf(sqrtf(norms[row]), 1e-12f) * TAU);
    const int lab = labs[row];
    float den = 0.f, num = 0.f;
#pragma unroll
    for (int t = 0; t < 4; ++t) {
      const float e = __expf(acc[t][r] * sc);
      den += e;
      if ((t * 16 + m) == lab) num += e;
    }
#pragma unroll
    for (int d = 1; d < 16; d <<= 1) {     // reduce across the 16 n-lanes
      den += __shfl_xor(den, d, 64);
      num += __shfl_xor(num, d, 64);
    }
    if (m == 0) lossAcc += -__logf((num + EPS) / (den + EPS) + EPS);
  }

  red[tid] = lossAcc;
  __syncthreads();
#pragma unroll
  for (int s = 128; s > 0; s >>= 1) {
    if (tid < s) red[tid] += red[tid + s];
    __syncthreads();
  }
  if (tid == 0) atomicAdd(acc_out, (double)red[0]);
}

// Kernel 3: mean -> out
__global__ void finalize_k(const double* __restrict__ acc,
                           float* __restrict__ out, double invB) {
  if (threadIdx.x == 0 && blockIdx.x == 0)
    out[0] = (float)(*acc * invB);
}

extern "C" void kernel_launch(void* const* d_in, const int* in_sizes, int n_in,
                              void* d_out, int out_size, void* d_ws, size_t ws_size,
                              hipStream_t stream) {
  const float* feat = (const float*)d_in[0];
  const float* protos = (const float*)d_in[1];
  const int* labels = (const int*)d_in[2];
  float* out = (float*)d_out;
  const int Bn = in_sizes[0] / 256;        // 262144 rows
  double* acc = (double*)d_ws;
  unsigned short* pbf = (unsigned short*)((char*)d_ws + 16);

  hipLaunchKernelGGL(proto_prep, dim3(1), dim3(256), 0, stream, protos, pbf, acc);
  hipLaunchKernelGGL(protonce_main, dim3(Bn / 64), dim3(256), 0, stream,
                     feat, pbf, labels, acc);
  hipLaunchKernelGGL(finalize_k, dim3(1), dim3(64), 0, stream, acc, out,
                     1.0 / (double)Bn);
}

// Round 2
// 383.806 us; speedup vs baseline: 1.2345x; 1.2345x over previous
//
#include <hip/hip_runtime.h>
#include <stdint.h>

typedef __attribute__((ext_vector_type(8))) short short8;
typedef __attribute__((ext_vector_type(4))) float floatx4;

#define EPS 1e-8f
#define TAU 0.1f

// float -> bf16 bits, round-to-nearest-even
__device__ __forceinline__ unsigned short f2bf(float f) {
  union { float f; unsigned u; } v; v.f = f;
  unsigned u = v.u;
  u += 0x7fffu + ((u >> 16) & 1u);
  return (unsigned short)(u >> 16);
}

// Kernel 1: normalize prototypes (K=64 x D=256) -> bf16 row-major in ws.
// 16 blocks x 256 threads; one wave per prototype row.
__global__ void proto_prep(const float* __restrict__ protos,
                           unsigned short* __restrict__ pbf) {
  const int l = threadIdx.x & 63;
  const int w = threadIdx.x >> 6;
  const int row = blockIdx.x * 4 + w;
  float4 v = reinterpret_cast<const float4*>(protos)[row * 64 + l];
  float ss = v.x * v.x + v.y * v.y + v.z * v.z + v.w * v.w;
#pragma unroll
  for (int d = 1; d < 64; d <<= 1) ss += __shfl_xor(ss, d, 64);
  const float inv = 1.0f / fmaxf(sqrtf(ss), 1e-12f);
  ushort4 o;
  o.x = f2bf(v.x * inv); o.y = f2bf(v.y * inv);
  o.z = f2bf(v.z * inv); o.w = f2bf(v.w * inv);
  reinterpret_cast<ushort4*>(pbf)[row * 64 + l] = o;
}

// Kernel 2: main. Block = 64 rows, wave = 16 rows. A-fragments loaded
// directly from global (f32, coalesced 128B lines), norms from the same
// registers, bf16 convert in-register, B-fragments from L1/L2-resident pbf.
// No LDS staging, no barriers until the final 4-float block reduce.
__global__ void protonce_main(const float* __restrict__ feat,
                              const unsigned short* __restrict__ pbf,
                              const int* __restrict__ labels,
                              float* __restrict__ partials) {
  const int tid = threadIdx.x;
  const int l = tid & 63;
  const int w = tid >> 6;
  const int n = l & 15;                     // A: m-row; B/D: n-col
  const int q = l >> 4;                     // MFMA quad
  const long rowBase = (long)blockIdx.x * 64 + w * 16;

  // ---- Phase 1: batch-issue 16 independent 1KB wave-loads (A as f32) ----
  const float* arow = feat + (rowBase + n) * 256 + q * 8;
  float4 av[16];
#pragma unroll
  for (int s = 0; s < 8; ++s) {
    av[2 * s]     = *reinterpret_cast<const float4*>(arow + s * 32);
    av[2 * s + 1] = *reinterpret_cast<const float4*>(arow + s * 32 + 4);
  }

  // ---- Phase 2: f32 norm partials + bf16 fragment convert ----
  float ss = 0.f;
  short8 af[8];
#pragma unroll
  for (int s = 0; s < 8; ++s) {
    float4 x = av[2 * s], y = av[2 * s + 1];
    ss += x.x * x.x + x.y * x.y + x.z * x.z + x.w * x.w +
          y.x * y.x + y.y * y.y + y.z * y.z + y.w * y.w;
    short8 t;
    t[0] = f2bf(x.x); t[1] = f2bf(x.y); t[2] = f2bf(x.z); t[3] = f2bf(x.w);
    t[4] = f2bf(y.x); t[5] = f2bf(y.y); t[6] = f2bf(y.z); t[7] = f2bf(y.w);
    af[s] = t;
  }
  // combine the 4 q-chunks: every lane ends with ||f||^2 of row (l&15)
  ss += __shfl_xor(ss, 16, 64);
  ss += __shfl_xor(ss, 32, 64);

  // ---- Phase 3: MFMA (16x256)x(256x64), B-fragments from global ----
  floatx4 acc[4] = {{0.f, 0.f, 0.f, 0.f}, {0.f, 0.f, 0.f, 0.f},
                    {0.f, 0.f, 0.f, 0.f}, {0.f, 0.f, 0.f, 0.f}};
  const unsigned short* bbase = pbf + n * 256 + q * 8;
#pragma unroll
  for (int s = 0; s < 8; ++s) {
#pragma unroll
    for (int t = 0; t < 4; ++t) {
      short8 bf = *reinterpret_cast<const short8*>(bbase + t * 4096 + s * 32);
      acc[t] = __builtin_amdgcn_mfma_f32_16x16x32_bf16(af[s], bf, acc[t], 0, 0, 0);
    }
  }

  // ---- Phase 4: epilogue. Lane holds sim[row=q*4+r][col=t*16+n] ----
  const int4 lv = *reinterpret_cast<const int4*>(labels + rowBase + q * 4);
  float lossAcc = 0.f;
#pragma unroll
  for (int r = 0; r < 4; ++r) {
    const int row = q * 4 + r;
    const float nrm = __shfl(ss, row, 64);  // bpermute: norm^2 of row
    const float sc = 1.0f / (fmaxf(sqrtf(nrm), 1e-12f) * TAU);
    const int lab = (r == 0) ? lv.x : (r == 1) ? lv.y : (r == 2) ? lv.z : lv.w;
    float den = 0.f, num = 0.f;
#pragma unroll
    for (int t = 0; t < 4; ++t) {
      const float e = __expf(acc[t][r] * sc);
      den += e;
      num += (t * 16 + n == lab) ? e : 0.f;
    }
#pragma unroll
    for (int d = 1; d < 16; d <<= 1) {
      den += __shfl_xor(den, d, 64);
      num += __shfl_xor(num, d, 64);
    }
    if (n == 0) lossAcc += -__logf((num + EPS) / (den + EPS) + EPS);
  }
  // wave total lives on lanes 0,16,32,48 -> combine to all lanes
  lossAcc += __shfl_xor(lossAcc, 16, 64);
  lossAcc += __shfl_xor(lossAcc, 32, 64);

  __shared__ float wsum[4];
  if (l == 0) wsum[w] = lossAcc;
  __syncthreads();
  if (tid == 0) partials[blockIdx.x] = wsum[0] + wsum[1] + wsum[2] + wsum[3];
}

// Kernel 3: deterministic reduce of per-block partials -> mean
__global__ void finalize_k(const float* __restrict__ partials, int nblocks,
                           float* __restrict__ out, float invB) {
  __shared__ float red[256];
  float s = 0.f;
  for (int i = threadIdx.x; i < nblocks; i += 256) s += partials[i];
  red[threadIdx.x] = s;
  __syncthreads();
#pragma unroll
  for (int d = 128; d > 0; d >>= 1) {
    if (threadIdx.x < d) red[threadIdx.x] += red[threadIdx.x + d];
    __syncthreads();
  }
  if (threadIdx.x == 0) out[0] = red[0] * invB;
}

extern "C" void kernel_launch(void* const* d_in, const int* in_sizes, int n_in,
                              void* d_out, int out_size, void* d_ws, size_t ws_size,
                              hipStream_t stream) {
  const float* feat = (const float*)d_in[0];
  const float* protos = (const float*)d_in[1];
  const int* labels = (const int*)d_in[2];
  float* out = (float*)d_out;
  const int Bn = in_sizes[0] / 256;            // 262144 rows
  const int nblocks = Bn / 64;                 // 4096
  unsigned short* pbf = (unsigned short*)d_ws; // 32 KB
  float* partials = (float*)((char*)d_ws + 64 * 256 * sizeof(unsigned short));

  hipLaunchKernelGGL(proto_prep, dim3(16), dim3(256), 0, stream, protos, pbf);
  hipLaunchKernelGGL(protonce_main, dim3(nblocks), dim3(256), 0, stream,
                     feat, pbf, labels, partials);
  hipLaunchKernelGGL(finalize_k, dim3(1), dim3(256), 0, stream, partials,
                     nblocks, out, 1.0f / (float)Bn);
}

// Round 3
// 377.419 us; speedup vs baseline: 1.2554x; 1.0169x over previous
//
#include <hip/hip_runtime.h>
#include <stdint.h>

typedef __attribute__((ext_vector_type(8))) short short8;
typedef __attribute__((ext_vector_type(4))) float floatx4;

#define EPS 1e-8f
#define TAU 0.1f

// float -> bf16 bits, round-to-nearest-even (used only in tiny prep kernel)
__device__ __forceinline__ unsigned short f2bf(float f) {
  union { float f; unsigned u; } v; v.f = f;
  unsigned u = v.u;
  u += 0x7fffu + ((u >> 16) & 1u);
  return (unsigned short)(u >> 16);
}

// pack two f32 -> {bf16(hi) , bf16(lo)} by truncation: ONE v_perm_b32.
// D = { hi16(b) , hi16(a) }  (a in low half)
__device__ __forceinline__ unsigned pack2_trunc(float lo, float hi) {
  union { float f; unsigned u; } a, b; a.f = lo; b.f = hi;
  return __builtin_amdgcn_perm(b.u, a.u, 0x07060302u);
}

// Kernel 1: normalize prototypes (K=64 x D=256) -> bf16 row-major in ws.
__global__ void proto_prep(const float* __restrict__ protos,
                           unsigned short* __restrict__ pbf) {
  const int l = threadIdx.x & 63;
  const int w = threadIdx.x >> 6;
  const int row = blockIdx.x * 4 + w;
  float4 v = reinterpret_cast<const float4*>(protos)[row * 64 + l];
  float ss = v.x * v.x + v.y * v.y + v.z * v.z + v.w * v.w;
#pragma unroll
  for (int d = 1; d < 64; d <<= 1) ss += __shfl_xor(ss, d, 64);
  const float inv = 1.0f / fmaxf(sqrtf(ss), 1e-12f);
  ushort4 o;
  o.x = f2bf(v.x * inv); o.y = f2bf(v.y * inv);
  o.z = f2bf(v.z * inv); o.w = f2bf(v.w * inv);
  reinterpret_cast<ushort4*>(pbf)[row * 64 + l] = o;
}

// Kernel 2: main. Block = 64 rows, wave = 16 rows. Software-pipelined A
// loads (4-stage rotating buffer, 32 VGPRs in flight), truncation bf16
// pack (1 v_perm per pair), MFMA against L1/L2-resident pbf.
// __launch_bounds__(256,4): cap VGPR at 128 -> 4 waves/SIMD.
__global__ __launch_bounds__(256, 4)
void protonce_main(const float* __restrict__ feat,
                   const unsigned short* __restrict__ pbf,
                   const int* __restrict__ labels,
                   float* __restrict__ partials) {
  const int tid = threadIdx.x;
  const int l = tid & 63;
  const int w = tid >> 6;
  const int n = l & 15;                     // A: m-row; B/D: n-col
  const int q = l >> 4;                     // MFMA quad
  const long rowBase = (long)blockIdx.x * 64 + w * 16;

  const float* arow = feat + (rowBase + n) * 256 + q * 8;
  const unsigned short* bbase = pbf + n * 256 + q * 8;

  // 4-stage prefetch pipeline for the 8 K-steps (8 floats = 32B per step)
  float4 avx[4], avy[4];
#pragma unroll
  for (int i = 0; i < 4; ++i) {
    avx[i] = *reinterpret_cast<const float4*>(arow + i * 32);
    avy[i] = *reinterpret_cast<const float4*>(arow + i * 32 + 4);
  }

  floatx4 acc[4] = {{0.f, 0.f, 0.f, 0.f}, {0.f, 0.f, 0.f, 0.f},
                    {0.f, 0.f, 0.f, 0.f}, {0.f, 0.f, 0.f, 0.f}};
  float ss = 0.f;

#pragma unroll
  for (int s = 0; s < 8; ++s) {
    float4 x = avx[s & 3], y = avy[s & 3];
    if (s < 4) {                            // prefetch step s+4 into this slot
      avx[s & 3] = *reinterpret_cast<const float4*>(arow + (s + 4) * 32);
      avy[s & 3] = *reinterpret_cast<const float4*>(arow + (s + 4) * 32 + 4);
    }
    ss += x.x * x.x + x.y * x.y + x.z * x.z + x.w * x.w +
          y.x * y.x + y.y * y.y + y.z * y.z + y.w * y.w;
    union { short8 s8; uint4 u4; } af;
    af.u4.x = pack2_trunc(x.x, x.y);
    af.u4.y = pack2_trunc(x.z, x.w);
    af.u4.z = pack2_trunc(y.x, y.y);
    af.u4.w = pack2_trunc(y.z, y.w);
#pragma unroll
    for (int t = 0; t < 4; ++t) {
      short8 bf = *reinterpret_cast<const short8*>(bbase + t * 4096 + s * 32);
      acc[t] = __builtin_amdgcn_mfma_f32_16x16x32_bf16(af.s8, bf, acc[t], 0, 0, 0);
    }
  }

  // every lane ends with full ||f||^2 of row (l&15)
  ss += __shfl_xor(ss, 16, 64);
  ss += __shfl_xor(ss, 32, 64);

  // Epilogue. Lane holds sim[row=q*4+r][col=t*16+n]
  const int4 lv = *reinterpret_cast<const int4*>(labels + rowBase + q * 4);
  float lossAcc = 0.f;
#pragma unroll
  for (int r = 0; r < 4; ++r) {
    const int row = q * 4 + r;
    const float nrm = __shfl(ss, row, 64);
    const float sc = 1.0f / (fmaxf(sqrtf(nrm), 1e-12f) * TAU);
    const int lab = (r == 0) ? lv.x : (r == 1) ? lv.y : (r == 2) ? lv.z : lv.w;
    float den = 0.f, num = 0.f;
#pragma unroll
    for (int t = 0; t < 4; ++t) {
      const float e = __expf(acc[t][r] * sc);
      den += e;
      num += (t * 16 + n == lab) ? e : 0.f;
    }
#pragma unroll
    for (int d = 1; d < 16; d <<= 1) {
      den += __shfl_xor(den, d, 64);
      num += __shfl_xor(num, d, 64);
    }
    if (n == 0) lossAcc += -__logf((num + EPS) / (den + EPS) + EPS);
  }
  lossAcc += __shfl_xor(lossAcc, 16, 64);
  lossAcc += __shfl_xor(lossAcc, 32, 64);

  __shared__ float wsum[4];
  if (l == 0) wsum[w] = lossAcc;
  __syncthreads();
  if (tid == 0) partials[blockIdx.x] = wsum[0] + wsum[1] + wsum[2] + wsum[3];
}

// Kernel 3: deterministic reduce of per-block partials -> mean
__global__ void finalize_k(const float* __restrict__ partials, int nblocks,
                           float* __restrict__ out, float invB) {
  __shared__ float red[256];
  float s = 0.f;
  for (int i = threadIdx.x; i < nblocks; i += 256) s += partials[i];
  red[threadIdx.x] = s;
  __syncthreads();
#pragma unroll
  for (int d = 128; d > 0; d >>= 1) {
    if (threadIdx.x < d) red[threadIdx.x] += red[threadIdx.x + d];
    __syncthreads();
  }
  if (threadIdx.x == 0) out[0] = red[0] * invB;
}

extern "C" void kernel_launch(void* const* d_in, const int* in_sizes, int n_in,
                              void* d_out, int out_size, void* d_ws, size_t ws_size,
                              hipStream_t stream) {
  const float* feat = (const float*)d_in[0];
  const float* protos = (const float*)d_in[1];
  const int* labels = (const int*)d_in[2];
  float* out = (float*)d_out;
  const int Bn = in_sizes[0] / 256;            // 262144 rows
  const int nblocks = Bn / 64;                 // 4096
  unsigned short* pbf = (unsigned short*)d_ws; // 32 KB
  float* partials = (float*)((char*)d_ws + 64 * 256 * sizeof(unsigned short));

  hipLaunchKernelGGL(proto_prep, dim3(16), dim3(256), 0, stream, protos, pbf);
  hipLaunchKernelGGL(protonce_main, dim3(nblocks), dim3(256), 0, stream,
                     feat, pbf, labels, partials);
  hipLaunchKernelGGL(finalize_k, dim3(1), dim3(256), 0, stream, partials,
                     nblocks, out, 1.0f / (float)Bn);
}

// Round 4
// 367.464 us; speedup vs baseline: 1.2895x; 1.0271x over previous
//
#include <hip/hip_runtime.h>
#include <stdint.h>

typedef __attribute__((ext_vector_type(8))) short short8;
typedef __attribute__((ext_vector_type(4))) float floatx4;

#define EPS 1e-8f
#define TAU 0.1f
#define LROW 264   // dwords per LDS row: 256 data + 8 pad (264%32==8)

// float -> bf16 bits, round-to-nearest-even (prep kernel only)
__device__ __forceinline__ unsigned short f2bf(float f) {
  union { float f; unsigned u; } v; v.f = f;
  unsigned u = v.u;
  u += 0x7fffu + ((u >> 16) & 1u);
  return (unsigned short)(u >> 16);
}

// pack two f32 -> {bf16(hi), bf16(lo)} by truncation: one v_perm_b32
__device__ __forceinline__ unsigned pack2_trunc(float lo, float hi) {
  union { float f; unsigned u; } a, b; a.f = lo; b.f = hi;
  return __builtin_amdgcn_perm(b.u, a.u, 0x07060302u);
}

// async global->LDS DMA, 16B per lane: lane i reads g + i*16, lands at l + i*16
__device__ __forceinline__ void async_copy16(const void* g, void* l) {
  __builtin_amdgcn_global_load_lds(
      (__attribute__((address_space(1))) void*)g,
      (__attribute__((address_space(3))) void*)l, 16, 0, 0);
}

// Kernel 1: normalize prototypes (K=64 x D=256) -> bf16 row-major in ws.
__global__ void proto_prep(const float* __restrict__ protos,
                           unsigned short* __restrict__ pbf) {
  const int l = threadIdx.x & 63;
  const int w = threadIdx.x >> 6;
  const int row = blockIdx.x * 4 + w;
  float4 v = reinterpret_cast<const float4*>(protos)[row * 64 + l];
  float ss = v.x * v.x + v.y * v.y + v.z * v.z + v.w * v.w;
#pragma unroll
  for (int d = 1; d < 64; d <<= 1) ss += __shfl_xor(ss, d, 64);
  const float inv = 1.0f / fmaxf(sqrtf(ss), 1e-12f);
  ushort4 o;
  o.x = f2bf(v.x * inv); o.y = f2bf(v.y * inv);
  o.z = f2bf(v.z * inv); o.w = f2bf(v.w * inv);
  reinterpret_cast<ushort4*>(pbf)[row * 64 + l] = o;
}

// Kernel 2: main. Block = 32 rows. Waves 2x2: (mw = row-half, nw = proto-half).
// Async-stage the f32 tile to LDS (no VGPR round-trip), preload all B frags
// to registers during the DMA, one barrier, then a global-free MFMA loop.
__global__ __launch_bounds__(256, 4)
void protonce_main(const float* __restrict__ feat,
                   const unsigned short* __restrict__ pbf,
                   const int* __restrict__ labels,
                   float* __restrict__ partials) {
  __shared__ __align__(16) float At[32 * LROW];   // 33792 B
  __shared__ float dn_sm[2][32];
  __shared__ float nm_sm[2][32];

  const int tid = threadIdx.x;
  const int l = tid & 63;
  const int w = tid >> 6;
  const int mw = w & 1;                    // row-half: rows [mw*16, +16)
  const int nw = w >> 1;                   // proto-half: cols [nw*32, +32)
  const int n = l & 15;
  const int q = l >> 4;
  const long rowBase = (long)blockIdx.x * 32;

  // ---- stage: wave w DMAs rows w*8..w*8+7, 1KB coalesced per instr ----
  const float* srcw = feat + (rowBase + w * 8) * 256 + l * 4;
#pragma unroll
  for (int j = 0; j < 8; ++j)
    async_copy16(srcw + j * 256, &At[(w * 8 + j) * LROW]);

  // ---- preload B fragments (32 KB pbf, L1/L2 resident) during DMA ----
  const unsigned short* bbase = pbf + (nw * 32 + n) * 256 + q * 8;
  short8 bv[16];
#pragma unroll
  for (int s = 0; s < 8; ++s) {
    bv[2 * s]     = *reinterpret_cast<const short8*>(bbase + s * 32);
    bv[2 * s + 1] = *reinterpret_cast<const short8*>(bbase + 16 * 256 + s * 32);
  }

  __syncthreads();                          // drains DMA + B loads

  // ---- global-free hot loop: ds_read -> norm FMA -> pack -> MFMA ----
  floatx4 acc0 = {0.f, 0.f, 0.f, 0.f}, acc1 = {0.f, 0.f, 0.f, 0.f};
  float ss = 0.f;
  const float* arow = &At[(mw * 16 + n) * LROW + q * 8];
#pragma unroll
  for (int s = 0; s < 8; ++s) {
    float4 x = *reinterpret_cast<const float4*>(arow + s * 32);
    float4 y = *reinterpret_cast<const float4*>(arow + s * 32 + 4);
    ss += x.x * x.x + x.y * x.y + x.z * x.z + x.w * x.w +
          y.x * y.x + y.y * y.y + y.z * y.z + y.w * y.w;
    union { short8 s8; uint4 u4; } af;
    af.u4.x = pack2_trunc(x.x, x.y);
    af.u4.y = pack2_trunc(x.z, x.w);
    af.u4.z = pack2_trunc(y.x, y.y);
    af.u4.w = pack2_trunc(y.z, y.w);
    acc0 = __builtin_amdgcn_mfma_f32_16x16x32_bf16(af.s8, bv[2 * s],     acc0, 0, 0, 0);
    acc1 = __builtin_amdgcn_mfma_f32_16x16x32_bf16(af.s8, bv[2 * s + 1], acc1, 0, 0, 0);
  }
  // every lane: full ||f||^2 of row (mw*16 + n)
  ss += __shfl_xor(ss, 16, 64);
  ss += __shfl_xor(ss, 32, 64);

  // ---- epilogue: lane holds sim[row=q*4+r][col = nw*32 + {0,16} + n] ----
  const int4 lv = *reinterpret_cast<const int4*>(labels + rowBase + mw * 16 + q * 4);
#pragma unroll
  for (int r = 0; r < 4; ++r) {
    const float nrm = __shfl(ss, q * 4 + r, 64);   // lane q*4+r has n==q*4+r
    const float sc = 1.0f / (fmaxf(sqrtf(nrm), 1e-12f) * TAU);
    const int lab = (r == 0) ? lv.x : (r == 1) ? lv.y : (r == 2) ? lv.z : lv.w;
    const float e0 = __expf(acc0[r] * sc);
    const float e1 = __expf(acc1[r] * sc);
    float den = e0 + e1;
    float num = (nw * 32 + n == lab ? e0 : 0.f) + (nw * 32 + 16 + n == lab ? e1 : 0.f);
#pragma unroll
    for (int d = 1; d < 16; d <<= 1) {
      den += __shfl_xor(den, d, 64);
      num += __shfl_xor(num, d, 64);
    }
    if (n == 0) {
      dn_sm[nw][mw * 16 + q * 4 + r] = den;
      nm_sm[nw][mw * 16 + q * 4 + r] = num;
    }
  }
  __syncthreads();

  if (w == 0) {
    float loss = 0.f;
    if (l < 32) {
      const float den = dn_sm[0][l] + dn_sm[1][l];
      const float num = nm_sm[0][l] + nm_sm[1][l];
      loss = -__logf((num + EPS) / (den + EPS) + EPS);
    }
#pragma unroll
    for (int d = 1; d < 64; d <<= 1) loss += __shfl_xor(loss, d, 64);
    if (l == 0) partials[blockIdx.x] = loss;
  }
}

// Kernel 3: deterministic reduce of per-block partials -> mean
__global__ void finalize_k(const float* __restrict__ partials, int nblocks,
                           float* __restrict__ out, float invB) {
  __shared__ float red[256];
  float s = 0.f;
  for (int i = threadIdx.x; i < nblocks; i += 256) s += partials[i];
  red[threadIdx.x] = s;
  __syncthreads();
#pragma unroll
  for (int d = 128; d > 0; d >>= 1) {
    if (threadIdx.x < d) red[threadIdx.x] += red[threadIdx.x + d];
    __syncthreads();
  }
  if (threadIdx.x == 0) out[0] = red[0] * invB;
}

extern "C" void kernel_launch(void* const* d_in, const int* in_sizes, int n_in,
                              void* d_out, int out_size, void* d_ws, size_t ws_size,
                              hipStream_t stream) {
  const float* feat = (const float*)d_in[0];
  const float* protos = (const float*)d_in[1];
  const int* labels = (const int*)d_in[2];
  float* out = (float*)d_out;
  const int Bn = in_sizes[0] / 256;            // 262144 rows
  const int nblocks = Bn / 32;                 // 8192
  unsigned short* pbf = (unsigned short*)d_ws; // 32 KB
  float* partials = (float*)((char*)d_ws + 64 * 256 * sizeof(unsigned short));

  hipLaunchKernelGGL(proto_prep, dim3(16), dim3(256), 0, stream, protos, pbf);
  hipLaunchKernelGGL(protonce_main, dim3(nblocks), dim3(256), 0, stream,
                     feat, pbf, labels, partials);
  hipLaunchKernelGGL(finalize_k, dim3(1), dim3(256), 0, stream, partials,
                     nblocks, out, 1.0f / (float)Bn);
}